// Round 2
// baseline (604.482 us; speedup 1.0000x reference)
//
#include <hip/hip_runtime.h>
#include <stdint.h>
#include <math.h>

// ---------------- workspace layout (bytes) ----------------
#define OFF_S1   0           // float2[32]
#define OFF_S2   256         // float2[64]
#define OFF_S3   768         // float2[128]
#define OFF_S4   1792        // float2[256]
#define OFF_W2   3840        // uint32[64*9]
#define OFF_W3   6144        // uint64[128*9]
#define OFF_W4   15360       // uint64[256*9*2]
#define OFF_A1   52224       // uint32[32*224*224]   6,422,528 B
#define OFF_A2   6474752     // uint64[32*112*112]   3,211,264 B
#define OFF_A3   9686016     // uint64[32*56*56*2]   1,605,632 B
#define OFF_A4   11291648    // uint64[32*28*28*4]     802,816 B
// total ~12.1 MB

// BN(x) >= 0 decided exactly as np fp32 would: fl(fl(x*sc)+sh) >= 0
static __device__ __forceinline__ float2 bnf(float g, float b, float m, float v) {
    float sc = __fdiv_rn(g, __fsqrt_rn(__fadd_rn(v, 1e-5f)));
    float sh = __fsub_rn(b, __fmul_rn(m, sc));
    return make_float2(sc, sh);
}
static __device__ __forceinline__ bool bnpos(float s, float2 p) {
    return __fadd_rn(__fmul_rn(s, p.x), p.y) >= 0.0f;
}

// ---------------- prep: BN scale/shift + packed binarized weights ----------------
__global__ __launch_bounds__(256) void k_prep(
    const float* __restrict__ w2, const float* __restrict__ w3, const float* __restrict__ w4,
    const float* g1, const float* b1, const float* m1, const float* v1,
    const float* g2, const float* b2, const float* m2, const float* v2,
    const float* g3, const float* b3, const float* m3, const float* v3,
    const float* g4, const float* b4, const float* m4, const float* v4,
    float2* __restrict__ S1, float2* __restrict__ S2, float2* __restrict__ S3, float2* __restrict__ S4,
    uint32_t* __restrict__ W2, uint64_t* __restrict__ W3, uint64_t* __restrict__ W4)
{
    int tid = threadIdx.x;
    if (tid < 32)  S1[tid] = bnf(g1[tid], b1[tid], m1[tid], v1[tid]);
    if (tid < 64)  S2[tid] = bnf(g2[tid], b2[tid], m2[tid], v2[tid]);
    if (tid < 128) S3[tid] = bnf(g3[tid], b3[tid], m3[tid], v3[tid]);
    S4[tid] = bnf(g4[tid], b4[tid], m4[tid], v4[tid]);

    // W2: conv2_w [64][32][3][3] -> [oc][tap] u32 over 32 in-ch; bit ic = (w >= 0)
    if (tid < 64) {
        int oc = tid;
        for (int t = 0; t < 9; t++) {
            uint32_t bits = 0;
            for (int ic = 0; ic < 32; ic++)
                bits |= (uint32_t)(w2[oc * 288 + ic * 9 + t] >= 0.0f) << ic;
            W2[oc * 9 + t] = bits;
        }
    }
    // W3: conv3_w [128][64][3][3] -> [oc][tap] u64
    if (tid < 128) {
        int oc = tid;
        for (int t = 0; t < 9; t++) {
            uint64_t bits = 0;
            for (int ic = 0; ic < 64; ic++)
                bits |= (uint64_t)(w3[oc * 576 + ic * 9 + t] >= 0.0f) << ic;
            W3[oc * 9 + t] = bits;
        }
    }
    // W4: conv4_w [256][128][3][3] -> [oc][tap][word] u64 x2
    {
        int oc = tid;
        for (int t = 0; t < 9; t++) {
            uint64_t lo = 0, hi = 0;
            for (int ic = 0; ic < 64; ic++) {
                lo |= (uint64_t)(w4[oc * 1152 + ic * 9 + t] >= 0.0f) << ic;
                hi |= (uint64_t)(w4[oc * 1152 + (ic + 64) * 9 + t] >= 0.0f) << ic;
            }
            W4[oc * 18 + t * 2 + 0] = lo;
            W4[oc * 18 + t * 2 + 1] = hi;
        }
    }
}

// ---------------- conv1 (real, fp32) + bn1 + binarize + pack ----------------
// x: [32][3][224][224] f32 ; out A1: [32][224][224] u32 (bit oc)
// weights in LDS transposed [k][oc] as float4 groups for broadcast ds_read_b128
__global__ __launch_bounds__(256) void k_conv1(
    const float* __restrict__ x, const float* __restrict__ w1,
    const float2* __restrict__ S1g, uint32_t* __restrict__ A1)
{
    __shared__ float  wl[27 * 32];   // [k][oc]
    __shared__ float2 s1[32];
    int tid = threadIdx.x;
    for (int i = tid; i < 864; i += 256) {
        int k = i >> 5, oc = i & 31;
        wl[i] = w1[oc * 27 + k];     // w1 layout [oc][ic*9+tap]
    }
    if (tid < 32) s1[tid] = S1g[tid];
    __syncthreads();

    int idx = blockIdx.x * 256 + tid;       // b*50176 + y*224 + x
    int xc = idx % 224;
    int t  = idx / 224;
    int y  = t % 224;
    int b  = t / 224;

    const float* xb = x + (size_t)b * 3 * 50176;
    float xv[27];
    #pragma unroll
    for (int ic = 0; ic < 3; ic++)
        #pragma unroll
        for (int ky = 0; ky < 3; ky++)
            #pragma unroll
            for (int kx = 0; kx < 3; kx++) {
                int iy = y - 1 + ky, ix = xc - 1 + kx;
                float v = 0.0f;
                if ((unsigned)iy < 224u && (unsigned)ix < 224u)
                    v = xb[ic * 50176 + iy * 224 + ix];
                xv[ic * 9 + ky * 3 + kx] = v;
            }

    float acc[32];
    #pragma unroll
    for (int oc = 0; oc < 32; oc++) acc[oc] = 0.0f;

    const float4* wl4 = (const float4*)wl;
    #pragma unroll
    for (int k = 0; k < 27; k++) {
        float xk = xv[k];
        #pragma unroll
        for (int g8 = 0; g8 < 8; g8++) {
            float4 w = wl4[k * 8 + g8];
            acc[g8 * 4 + 0] = fmaf(xk, w.x, acc[g8 * 4 + 0]);
            acc[g8 * 4 + 1] = fmaf(xk, w.y, acc[g8 * 4 + 1]);
            acc[g8 * 4 + 2] = fmaf(xk, w.z, acc[g8 * 4 + 2]);
            acc[g8 * 4 + 3] = fmaf(xk, w.w, acc[g8 * 4 + 3]);
        }
    }

    uint32_t bits = 0;
    #pragma unroll
    for (int oc = 0; oc < 32; oc++)
        bits |= (uint32_t)bnpos(acc[oc], s1[oc]) << oc;
    A1[idx] = bits;
}

// ---------------- conv2 (binary, stride 2) + bn2 + binarize + pack ----------------
// A1: [32][224][224] u32 -> A2: [32][112][112] u64
__global__ __launch_bounds__(256) void k_conv2(
    const uint32_t* __restrict__ A1, const uint32_t* __restrict__ W2,
    const float2* __restrict__ S2g, uint64_t* __restrict__ A2)
{
    __shared__ uint32_t wl[64 * 9];
    __shared__ float2   s2[64];
    int tid = threadIdx.x;
    for (int i = tid; i < 576; i += 256) wl[i] = W2[i];
    if (tid < 64) s2[tid] = S2g[tid];
    __syncthreads();

    int idx = blockIdx.x * 256 + tid;       // 32*112*112
    int ox = idx % 112;
    int t  = idx / 112;
    int oy = t % 112;
    int b  = t / 112;

    const uint32_t* ab = A1 + (size_t)b * 50176;
    uint32_t xw[9];
    unsigned vm = 0;
    #pragma unroll
    for (int ky = 0; ky < 3; ky++)
        #pragma unroll
        for (int kx = 0; kx < 3; kx++) {
            int iy = 2 * oy - 1 + ky, ix = 2 * ox - 1 + kx;
            int ti = ky * 3 + kx;
            bool ok = ((unsigned)iy < 224u) && ((unsigned)ix < 224u);
            xw[ti] = ok ? ab[iy * 224 + ix] : 0u;
            vm |= (unsigned)ok << ti;
        }

    uint64_t bits = 0;
    if (vm == 0x1FFu) {
        for (int oc = 0; oc < 64; oc++) {
            int pc = 0;
            #pragma unroll
            for (int ti = 0; ti < 9; ti++) pc += __popc(xw[ti] ^ wl[oc * 9 + ti]);
            bits |= (uint64_t)bnpos((float)(288 - 2 * pc), s2[oc]) << oc;
        }
    } else {
        for (int oc = 0; oc < 64; oc++) {
            int s = 0;
            #pragma unroll
            for (int ti = 0; ti < 9; ti++)
                if ((vm >> ti) & 1u) s += 32 - 2 * __popc(xw[ti] ^ wl[oc * 9 + ti]);
            bits |= (uint64_t)bnpos((float)s, s2[oc]) << oc;
        }
    }
    A2[idx] = bits;
}

// ---------------- conv3 (binary, stride 2) + bn3 + binarize + pack ----------------
// A2: [32][112][112] u64 -> A3: [32][56][56][2] u64 (128 out ch in 2 words)
__global__ __launch_bounds__(256) void k_conv3(
    const uint64_t* __restrict__ A2, const uint64_t* __restrict__ W3,
    const float2* __restrict__ S3g, uint64_t* __restrict__ A3)
{
    __shared__ uint64_t wl[128 * 9];
    __shared__ float2   s3[128];
    int tid = threadIdx.x;
    for (int i = tid; i < 1152; i += 256) wl[i] = W3[i];
    if (tid < 128) s3[tid] = S3g[tid];
    __syncthreads();

    int idx = blockIdx.x * 256 + tid;       // 32*56*56*2
    int g  = idx & 1;
    int p  = idx >> 1;
    int ox = p % 56;
    int t  = p / 56;
    int oy = t % 56;
    int b  = t / 56;

    const uint64_t* ab = A2 + (size_t)b * 12544;
    uint64_t xw[9];
    unsigned vm = 0;
    #pragma unroll
    for (int ky = 0; ky < 3; ky++)
        #pragma unroll
        for (int kx = 0; kx < 3; kx++) {
            int iy = 2 * oy - 1 + ky, ix = 2 * ox - 1 + kx;
            int ti = ky * 3 + kx;
            bool ok = ((unsigned)iy < 112u) && ((unsigned)ix < 112u);
            xw[ti] = ok ? ab[iy * 112 + ix] : 0ull;
            vm |= (unsigned)ok << ti;
        }

    int ocbase = g * 64;
    uint64_t bits = 0;
    if (vm == 0x1FFu) {
        for (int o = 0; o < 64; o++) {
            int oc = ocbase + o;
            int pc = 0;
            #pragma unroll
            for (int ti = 0; ti < 9; ti++) pc += __popcll(xw[ti] ^ wl[oc * 9 + ti]);
            bits |= (uint64_t)bnpos((float)(576 - 2 * pc), s3[oc]) << o;
        }
    } else {
        for (int o = 0; o < 64; o++) {
            int oc = ocbase + o;
            int s = 0;
            #pragma unroll
            for (int ti = 0; ti < 9; ti++)
                if ((vm >> ti) & 1u) s += 64 - 2 * __popcll(xw[ti] ^ wl[oc * 9 + ti]);
            bits |= (uint64_t)bnpos((float)s, s3[oc]) << o;
        }
    }
    A3[idx] = bits;   // [b][y][x][g]
}

// ---------------- conv4 (binary, stride 2) + bn4 + binarize + pack ----------------
// A3: [32][56][56][2] u64 -> A4: [32][28][28][4] u64 (256 out ch in 4 words)
__global__ __launch_bounds__(256) void k_conv4(
    const uint64_t* __restrict__ A3, const uint64_t* __restrict__ W4,
    const float2* __restrict__ S4g, uint64_t* __restrict__ A4)
{
    __shared__ uint64_t wl[256 * 9 * 2];    // 36,864 B
    __shared__ float2   s4[256];
    int tid = threadIdx.x;
    for (int i = tid; i < 4608; i += 256) wl[i] = W4[i];
    s4[tid] = S4g[tid];
    __syncthreads();

    int idx = blockIdx.x * 256 + tid;       // 32*28*28*4
    int g  = idx & 3;
    int p  = idx >> 2;
    int ox = p % 28;
    int t  = p / 28;
    int oy = t % 28;
    int b  = t / 28;

    const uint64_t* ab = A3 + (size_t)b * 3136 * 2;
    uint64_t x0[9], x1[9];
    unsigned vm = 0;
    #pragma unroll
    for (int ky = 0; ky < 3; ky++)
        #pragma unroll
        for (int kx = 0; kx < 3; kx++) {
            int iy = 2 * oy - 1 + ky, ix = 2 * ox - 1 + kx;
            int ti = ky * 3 + kx;
            bool ok = ((unsigned)iy < 56u) && ((unsigned)ix < 56u);
            int base = (iy * 56 + ix) * 2;
            x0[ti] = ok ? ab[base + 0] : 0ull;
            x1[ti] = ok ? ab[base + 1] : 0ull;
            vm |= (unsigned)ok << ti;
        }

    int ocbase = g * 64;
    uint64_t bits = 0;
    if (vm == 0x1FFu) {
        for (int o = 0; o < 64; o++) {
            int oc = ocbase + o;
            int pc = 0;
            #pragma unroll
            for (int ti = 0; ti < 9; ti++) {
                pc += __popcll(x0[ti] ^ wl[oc * 18 + ti * 2 + 0]);
                pc += __popcll(x1[ti] ^ wl[oc * 18 + ti * 2 + 1]);
            }
            bits |= (uint64_t)bnpos((float)(1152 - 2 * pc), s4[oc]) << o;
        }
    } else {
        for (int o = 0; o < 64; o++) {
            int oc = ocbase + o;
            int s = 0;
            #pragma unroll
            for (int ti = 0; ti < 9; ti++)
                if ((vm >> ti) & 1u) {
                    int pc = __popcll(x0[ti] ^ wl[oc * 18 + ti * 2 + 0])
                           + __popcll(x1[ti] ^ wl[oc * 18 + ti * 2 + 1]);
                    s += 128 - 2 * pc;
                }
            bits |= (uint64_t)bnpos((float)s, s4[oc]) << o;
        }
    }
    A4[idx] = bits;   // [b][y][x][g]
}

// ---------------- mean over HxW + fc ----------------
__global__ __launch_bounds__(256) void k_tail(
    const uint64_t* __restrict__ A4, const float* __restrict__ fcw,
    const float* __restrict__ fcb, float* __restrict__ out)
{
    int b = blockIdx.x;
    int c = threadIdx.x;            // channel 0..255
    int g = c >> 6, bit = c & 63;
    const uint64_t* ab = A4 + (size_t)b * 784 * 4;
    int cnt = 0;
    for (int p = 0; p < 784; p++) cnt += (int)((ab[p * 4 + g] >> bit) & 1ull);
    double mean = (2.0 * (double)cnt - 784.0) * (1.0 / 784.0);
    double p0 = (double)fcw[c]       * mean;   // fc_w[0][c]
    double p1 = (double)fcw[256 + c] * mean;   // fc_w[1][c]

    __shared__ double r0[256], r1[256];
    r0[c] = p0; r1[c] = p1;
    __syncthreads();
    for (int s = 128; s > 0; s >>= 1) {
        if (c < s) { r0[c] += r0[c + s]; r1[c] += r1[c + s]; }
        __syncthreads();
    }
    if (c == 0) {
        out[b * 2 + 0] = (float)(r0[0] + (double)fcb[0]);
        out[b * 2 + 1] = (float)(r1[0] + (double)fcb[1]);
    }
}

extern "C" void kernel_launch(void* const* d_in, const int* in_sizes, int n_in,
                              void* d_out, int out_size, void* d_ws, size_t ws_size,
                              hipStream_t stream) {
    const float* x   = (const float*)d_in[0];
    const float* w1  = (const float*)d_in[1];
    const float* w2  = (const float*)d_in[2];
    const float* w3  = (const float*)d_in[3];
    const float* w4  = (const float*)d_in[4];
    const float* g1 = (const float*)d_in[5],  *b1 = (const float*)d_in[6],
               * m1 = (const float*)d_in[7],  *v1 = (const float*)d_in[8];
    const float* g2 = (const float*)d_in[9],  *b2 = (const float*)d_in[10],
               * m2 = (const float*)d_in[11], *v2 = (const float*)d_in[12];
    const float* g3 = (const float*)d_in[13], *b3 = (const float*)d_in[14],
               * m3 = (const float*)d_in[15], *v3 = (const float*)d_in[16];
    const float* g4 = (const float*)d_in[17], *b4 = (const float*)d_in[18],
               * m4 = (const float*)d_in[19], *v4 = (const float*)d_in[20];
    const float* fcw = (const float*)d_in[21];
    const float* fcb = (const float*)d_in[22];
    float* out = (float*)d_out;

    char* ws = (char*)d_ws;
    float2*   S1 = (float2*)(ws + OFF_S1);
    float2*   S2 = (float2*)(ws + OFF_S2);
    float2*   S3 = (float2*)(ws + OFF_S3);
    float2*   S4 = (float2*)(ws + OFF_S4);
    uint32_t* W2 = (uint32_t*)(ws + OFF_W2);
    uint64_t* W3 = (uint64_t*)(ws + OFF_W3);
    uint64_t* W4 = (uint64_t*)(ws + OFF_W4);
    uint32_t* A1 = (uint32_t*)(ws + OFF_A1);
    uint64_t* A2 = (uint64_t*)(ws + OFF_A2);
    uint64_t* A3 = (uint64_t*)(ws + OFF_A3);
    uint64_t* A4 = (uint64_t*)(ws + OFF_A4);

    hipLaunchKernelGGL(k_prep, dim3(1), dim3(256), 0, stream,
                       w2, w3, w4,
                       g1, b1, m1, v1, g2, b2, m2, v2,
                       g3, b3, m3, v3, g4, b4, m4, v4,
                       S1, S2, S3, S4, W2, W3, W4);
    hipLaunchKernelGGL(k_conv1, dim3(6272), dim3(256), 0, stream, x, w1, S1, A1);
    hipLaunchKernelGGL(k_conv2, dim3(1568), dim3(256), 0, stream, A1, W2, S2, A2);
    hipLaunchKernelGGL(k_conv3, dim3(784),  dim3(256), 0, stream, A2, W3, S3, A3);
    hipLaunchKernelGGL(k_conv4, dim3(392),  dim3(256), 0, stream, A3, W4, S4, A4);
    hipLaunchKernelGGL(k_tail,  dim3(32),   dim3(256), 0, stream, A4, fcw, fcb, out);
}

// Round 3
// 379.007 us; speedup vs baseline: 1.5949x; 1.5949x over previous
//
#include <hip/hip_runtime.h>
#include <stdint.h>
#include <math.h>

// ---------------- workspace layout (bytes) ----------------
#define OFF_S1   0           // float2[32]
#define OFF_S2   256         // float2[64]
#define OFF_S3   768         // float2[128]
#define OFF_S4   1792        // float2[256]
#define OFF_W2   3840        // uint32[64*9]
#define OFF_W3   6144        // uint64[128*9]
#define OFF_W4   15360       // uint64[256*9*2]
#define OFF_A1   52224       // uint32[32*224*224]   6,422,528 B
#define OFF_A2   6474752     // uint64[32*112*112]   3,211,264 B
#define OFF_A3   9686016     // uint64[32*56*56*2]   1,605,632 B
#define OFF_A4   11291648    // uint64[32*28*28*4]     802,816 B
// total ~12.1 MB

// BN(x) >= 0 decided exactly as np fp32 would: fl(fl(x*sc)+sh) >= 0
static __device__ __forceinline__ float2 bnf(float g, float b, float m, float v) {
    float sc = __fdiv_rn(g, __fsqrt_rn(__fadd_rn(v, 1e-5f)));
    float sh = __fsub_rn(b, __fmul_rn(m, sc));
    return make_float2(sc, sh);
}
static __device__ __forceinline__ bool bnpos(float s, float2 p) {
    return __fadd_rn(__fmul_rn(s, p.x), p.y) >= 0.0f;
}

// ---------------- prep: ballot-parallel weight packing + BN params ----------------
// wave-task map: wid 0..575 -> W2 word; 576..1727 -> W3 word; 1728..6335 -> W4 word;
//                6336..6343 -> BN scale/shift channels
__global__ __launch_bounds__(256) void k_prep(
    const float* __restrict__ w2, const float* __restrict__ w3, const float* __restrict__ w4,
    const float* g1, const float* b1, const float* m1, const float* v1,
    const float* g2, const float* b2, const float* m2, const float* v2,
    const float* g3, const float* b3, const float* m3, const float* v3,
    const float* g4, const float* b4, const float* m4, const float* v4,
    float2* __restrict__ S1, float2* __restrict__ S2, float2* __restrict__ S3, float2* __restrict__ S4,
    uint32_t* __restrict__ W2, uint64_t* __restrict__ W3, uint64_t* __restrict__ W4)
{
    int gtid = blockIdx.x * 256 + threadIdx.x;
    int wid  = gtid >> 6;
    int lane = gtid & 63;

    if (wid < 576) {
        // W2: conv2_w [64][32][3][3]; bit ic = (w >= 0); lane = ic (<32)
        int oc = wid / 9, t = wid - oc * 9;
        float v = (lane < 32) ? w2[oc * 288 + lane * 9 + t] : -1.0f;
        uint64_t m = __ballot(v >= 0.0f);
        if (lane == 0) W2[wid] = (uint32_t)m;
    } else if (wid < 1728) {
        // W3: conv3_w [128][64][3][3]; lane = ic
        int i = wid - 576;
        int oc = i / 9, t = i - oc * 9;
        float v = w3[oc * 576 + lane * 9 + t];
        uint64_t m = __ballot(v >= 0.0f);
        if (lane == 0) W3[i] = m;
    } else if (wid < 6336) {
        // W4: conv4_w [256][128][3][3]; word = oc*18 + t*2 + h; lane = ic within half
        int i = wid - 1728;
        int oc = i / 18, rem = i - oc * 18;
        int t = rem >> 1, h = rem & 1;
        float v = w4[oc * 1152 + (h * 64 + lane) * 9 + t];
        uint64_t m = __ballot(v >= 0.0f);
        if (lane == 0) W4[i] = m;
    } else {
        int ch = (wid - 6336) * 64 + lane;   // 0..511
        if (ch < 32) {
            S1[ch] = bnf(g1[ch], b1[ch], m1[ch], v1[ch]);
        } else if (ch < 96) {
            int c = ch - 32;  S2[c] = bnf(g2[c], b2[c], m2[c], v2[c]);
        } else if (ch < 224) {
            int c = ch - 96;  S3[c] = bnf(g3[c], b3[c], m3[c], v3[c]);
        } else if (ch < 480) {
            int c = ch - 224; S4[c] = bnf(g4[c], b4[c], m4[c], v4[c]);
        }
    }
}

// ---------------- conv1 (real, fp32) + bn1 + binarize + pack ----------------
// x: [32][3][224][224] f32 ; out A1: [32][224][224] u32 (bit oc)
// 2 adjacent x-pixels per thread: weight ds_read_b128 amortized over 2x FMAs.
__global__ __launch_bounds__(256) void k_conv1(
    const float* __restrict__ x, const float* __restrict__ w1,
    const float2* __restrict__ S1g, uint32_t* __restrict__ A1)
{
    __shared__ float  wl[27 * 32];   // [k][oc]
    __shared__ float2 s1[32];
    int tid = threadIdx.x;
    for (int i = tid; i < 864; i += 256) {
        int k = i >> 5, oc = i & 31;
        wl[i] = w1[oc * 27 + k];     // w1 layout [oc][ic*9+tap]
    }
    if (tid < 32) s1[tid] = S1g[tid];
    __syncthreads();

    int idx = blockIdx.x * 256 + tid;       // [b][y][xpair], xpair 0..111
    int xp = idx % 112;
    int t  = idx / 112;
    int y  = t % 224;
    int b  = t / 224;
    int xc = xp * 2;

    const float* xb = x + (size_t)b * 3 * 50176;
    // input window: rows y-1..y+1, cols xc-1..xc+2, 3 ic
    float xin[3][3][4];
    #pragma unroll
    for (int ic = 0; ic < 3; ic++)
        #pragma unroll
        for (int ky = 0; ky < 3; ky++)
            #pragma unroll
            for (int cx = 0; cx < 4; cx++) {
                int iy = y - 1 + ky, ix = xc - 1 + cx;
                float v = 0.0f;
                if ((unsigned)iy < 224u && (unsigned)ix < 224u)
                    v = xb[ic * 50176 + iy * 224 + ix];
                xin[ic][ky][cx] = v;
            }

    float acc0[32], acc1[32];
    #pragma unroll
    for (int oc = 0; oc < 32; oc++) { acc0[oc] = 0.0f; acc1[oc] = 0.0f; }

    const float4* wl4 = (const float4*)wl;
    #pragma unroll
    for (int k = 0; k < 27; k++) {
        int ic = k / 9, r = (k % 9) / 3, c = k % 3;
        float a0 = xin[ic][r][c];
        float a1 = xin[ic][r][c + 1];
        #pragma unroll
        for (int g8 = 0; g8 < 8; g8++) {
            float4 w = wl4[k * 8 + g8];
            acc0[g8 * 4 + 0] = fmaf(a0, w.x, acc0[g8 * 4 + 0]);
            acc0[g8 * 4 + 1] = fmaf(a0, w.y, acc0[g8 * 4 + 1]);
            acc0[g8 * 4 + 2] = fmaf(a0, w.z, acc0[g8 * 4 + 2]);
            acc0[g8 * 4 + 3] = fmaf(a0, w.w, acc0[g8 * 4 + 3]);
            acc1[g8 * 4 + 0] = fmaf(a1, w.x, acc1[g8 * 4 + 0]);
            acc1[g8 * 4 + 1] = fmaf(a1, w.y, acc1[g8 * 4 + 1]);
            acc1[g8 * 4 + 2] = fmaf(a1, w.z, acc1[g8 * 4 + 2]);
            acc1[g8 * 4 + 3] = fmaf(a1, w.w, acc1[g8 * 4 + 3]);
        }
    }

    uint32_t bits0 = 0, bits1 = 0;
    #pragma unroll
    for (int oc = 0; oc < 32; oc++) {
        bits0 |= (uint32_t)bnpos(acc0[oc], s1[oc]) << oc;
        bits1 |= (uint32_t)bnpos(acc1[oc], s1[oc]) << oc;
    }
    // xc even -> 8B-aligned pair store
    uint2* dst = (uint2*)(A1 + (size_t)b * 50176 + y * 224 + xc);
    *dst = make_uint2(bits0, bits1);
}

// ---------------- conv2 (binary, stride 2) + bn2 + binarize + pack ----------------
// A1: [32][224][224] u32 -> A2: [32][112][112] u64
__global__ __launch_bounds__(256) void k_conv2(
    const uint32_t* __restrict__ A1, const uint32_t* __restrict__ W2,
    const float2* __restrict__ S2g, uint64_t* __restrict__ A2)
{
    __shared__ uint32_t wl[64 * 9];
    __shared__ float2   s2[64];
    int tid = threadIdx.x;
    for (int i = tid; i < 576; i += 256) wl[i] = W2[i];
    if (tid < 64) s2[tid] = S2g[tid];
    __syncthreads();

    int idx = blockIdx.x * 256 + tid;       // 32*112*112
    int ox = idx % 112;
    int t  = idx / 112;
    int oy = t % 112;
    int b  = t / 112;

    const uint32_t* ab = A1 + (size_t)b * 50176;
    uint32_t xw[9];
    unsigned vm = 0;
    #pragma unroll
    for (int ky = 0; ky < 3; ky++)
        #pragma unroll
        for (int kx = 0; kx < 3; kx++) {
            int iy = 2 * oy - 1 + ky, ix = 2 * ox - 1 + kx;
            int ti = ky * 3 + kx;
            bool ok = ((unsigned)iy < 224u) && ((unsigned)ix < 224u);
            xw[ti] = ok ? ab[iy * 224 + ix] : 0u;
            vm |= (unsigned)ok << ti;
        }

    uint64_t bits = 0;
    if (vm == 0x1FFu) {
        for (int oc = 0; oc < 64; oc++) {
            int pc = 0;
            #pragma unroll
            for (int ti = 0; ti < 9; ti++) pc += __popc(xw[ti] ^ wl[oc * 9 + ti]);
            bits |= (uint64_t)bnpos((float)(288 - 2 * pc), s2[oc]) << oc;
        }
    } else {
        for (int oc = 0; oc < 64; oc++) {
            int s = 0;
            #pragma unroll
            for (int ti = 0; ti < 9; ti++)
                if ((vm >> ti) & 1u) s += 32 - 2 * __popc(xw[ti] ^ wl[oc * 9 + ti]);
            bits |= (uint64_t)bnpos((float)s, s2[oc]) << oc;
        }
    }
    A2[idx] = bits;
}

// ---------------- conv3 (binary, stride 2) + bn3 + binarize + pack ----------------
// A2: [32][112][112] u64 -> A3: [32][56][56][2] u64 (128 out ch in 2 words)
__global__ __launch_bounds__(256) void k_conv3(
    const uint64_t* __restrict__ A2, const uint64_t* __restrict__ W3,
    const float2* __restrict__ S3g, uint64_t* __restrict__ A3)
{
    __shared__ uint64_t wl[128 * 9];
    __shared__ float2   s3[128];
    int tid = threadIdx.x;
    for (int i = tid; i < 1152; i += 256) wl[i] = W3[i];
    if (tid < 128) s3[tid] = S3g[tid];
    __syncthreads();

    int idx = blockIdx.x * 256 + tid;       // 32*56*56*2
    int g  = idx & 1;
    int p  = idx >> 1;
    int ox = p % 56;
    int t  = p / 56;
    int oy = t % 56;
    int b  = t / 56;

    const uint64_t* ab = A2 + (size_t)b * 12544;
    uint64_t xw[9];
    unsigned vm = 0;
    #pragma unroll
    for (int ky = 0; ky < 3; ky++)
        #pragma unroll
        for (int kx = 0; kx < 3; kx++) {
            int iy = 2 * oy - 1 + ky, ix = 2 * ox - 1 + kx;
            int ti = ky * 3 + kx;
            bool ok = ((unsigned)iy < 112u) && ((unsigned)ix < 112u);
            xw[ti] = ok ? ab[iy * 112 + ix] : 0ull;
            vm |= (unsigned)ok << ti;
        }

    int ocbase = g * 64;
    uint64_t bits = 0;
    if (vm == 0x1FFu) {
        for (int o = 0; o < 64; o++) {
            int oc = ocbase + o;
            int pc = 0;
            #pragma unroll
            for (int ti = 0; ti < 9; ti++) pc += __popcll(xw[ti] ^ wl[oc * 9 + ti]);
            bits |= (uint64_t)bnpos((float)(576 - 2 * pc), s3[oc]) << o;
        }
    } else {
        for (int o = 0; o < 64; o++) {
            int oc = ocbase + o;
            int s = 0;
            #pragma unroll
            for (int ti = 0; ti < 9; ti++)
                if ((vm >> ti) & 1u) s += 64 - 2 * __popcll(xw[ti] ^ wl[oc * 9 + ti]);
            bits |= (uint64_t)bnpos((float)s, s3[oc]) << o;
        }
    }
    A3[idx] = bits;   // [b][y][x][g]
}

// ---------------- conv4 (binary, stride 2) + bn4 + binarize + pack ----------------
// A3: [32][56][56][2] u64 -> A4: [32][28][28][4] u64 (256 out ch in 4 words)
__global__ __launch_bounds__(256) void k_conv4(
    const uint64_t* __restrict__ A3, const uint64_t* __restrict__ W4,
    const float2* __restrict__ S4g, uint64_t* __restrict__ A4)
{
    __shared__ uint64_t wl[256 * 9 * 2];    // 36,864 B
    __shared__ float2   s4[256];
    int tid = threadIdx.x;
    for (int i = tid; i < 4608; i += 256) wl[i] = W4[i];
    s4[tid] = S4g[tid];
    __syncthreads();

    int idx = blockIdx.x * 256 + tid;       // 32*28*28*4
    int g  = idx & 3;
    int p  = idx >> 2;
    int ox = p % 28;
    int t  = p / 28;
    int oy = t % 28;
    int b  = t / 28;

    const uint64_t* ab = A3 + (size_t)b * 3136 * 2;
    uint64_t x0[9], x1[9];
    unsigned vm = 0;
    #pragma unroll
    for (int ky = 0; ky < 3; ky++)
        #pragma unroll
        for (int kx = 0; kx < 3; kx++) {
            int iy = 2 * oy - 1 + ky, ix = 2 * ox - 1 + kx;
            int ti = ky * 3 + kx;
            bool ok = ((unsigned)iy < 56u) && ((unsigned)ix < 56u);
            int base = (iy * 56 + ix) * 2;
            x0[ti] = ok ? ab[base + 0] : 0ull;
            x1[ti] = ok ? ab[base + 1] : 0ull;
            vm |= (unsigned)ok << ti;
        }

    int ocbase = g * 64;
    uint64_t bits = 0;
    if (vm == 0x1FFu) {
        for (int o = 0; o < 64; o++) {
            int oc = ocbase + o;
            int pc = 0;
            #pragma unroll
            for (int ti = 0; ti < 9; ti++) {
                pc += __popcll(x0[ti] ^ wl[oc * 18 + ti * 2 + 0]);
                pc += __popcll(x1[ti] ^ wl[oc * 18 + ti * 2 + 1]);
            }
            bits |= (uint64_t)bnpos((float)(1152 - 2 * pc), s4[oc]) << o;
        }
    } else {
        for (int o = 0; o < 64; o++) {
            int oc = ocbase + o;
            int s = 0;
            #pragma unroll
            for (int ti = 0; ti < 9; ti++)
                if ((vm >> ti) & 1u) {
                    int pc = __popcll(x0[ti] ^ wl[oc * 18 + ti * 2 + 0])
                           + __popcll(x1[ti] ^ wl[oc * 18 + ti * 2 + 1]);
                    s += 128 - 2 * pc;
                }
            bits |= (uint64_t)bnpos((float)s, s4[oc]) << o;
        }
    }
    A4[idx] = bits;   // [b][y][x][g]
}

// ---------------- mean over HxW + fc ----------------
__global__ __launch_bounds__(256) void k_tail(
    const uint64_t* __restrict__ A4, const float* __restrict__ fcw,
    const float* __restrict__ fcb, float* __restrict__ out)
{
    int b = blockIdx.x;
    int c = threadIdx.x;            // channel 0..255
    int g = c >> 6, bit = c & 63;
    const uint64_t* ab = A4 + (size_t)b * 784 * 4;
    int cnt = 0;
    for (int p = 0; p < 784; p++) cnt += (int)((ab[p * 4 + g] >> bit) & 1ull);
    double mean = (2.0 * (double)cnt - 784.0) * (1.0 / 784.0);
    double p0 = (double)fcw[c]       * mean;   // fc_w[0][c]
    double p1 = (double)fcw[256 + c] * mean;   // fc_w[1][c]

    __shared__ double r0[256], r1[256];
    r0[c] = p0; r1[c] = p1;
    __syncthreads();
    for (int s = 128; s > 0; s >>= 1) {
        if (c < s) { r0[c] += r0[c + s]; r1[c] += r1[c + s]; }
        __syncthreads();
    }
    if (c == 0) {
        out[b * 2 + 0] = (float)(r0[0] + (double)fcb[0]);
        out[b * 2 + 1] = (float)(r1[0] + (double)fcb[1]);
    }
}

extern "C" void kernel_launch(void* const* d_in, const int* in_sizes, int n_in,
                              void* d_out, int out_size, void* d_ws, size_t ws_size,
                              hipStream_t stream) {
    const float* x   = (const float*)d_in[0];
    const float* w1  = (const float*)d_in[1];
    const float* w2  = (const float*)d_in[2];
    const float* w3  = (const float*)d_in[3];
    const float* w4  = (const float*)d_in[4];
    const float* g1 = (const float*)d_in[5],  *b1 = (const float*)d_in[6],
               * m1 = (const float*)d_in[7],  *v1 = (const float*)d_in[8];
    const float* g2 = (const float*)d_in[9],  *b2 = (const float*)d_in[10],
               * m2 = (const float*)d_in[11], *v2 = (const float*)d_in[12];
    const float* g3 = (const float*)d_in[13], *b3 = (const float*)d_in[14],
               * m3 = (const float*)d_in[15], *v3 = (const float*)d_in[16];
    const float* g4 = (const float*)d_in[17], *b4 = (const float*)d_in[18],
               * m4 = (const float*)d_in[19], *v4 = (const float*)d_in[20];
    const float* fcw = (const float*)d_in[21];
    const float* fcb = (const float*)d_in[22];
    float* out = (float*)d_out;

    char* ws = (char*)d_ws;
    float2*   S1 = (float2*)(ws + OFF_S1);
    float2*   S2 = (float2*)(ws + OFF_S2);
    float2*   S3 = (float2*)(ws + OFF_S3);
    float2*   S4 = (float2*)(ws + OFF_S4);
    uint32_t* W2 = (uint32_t*)(ws + OFF_W2);
    uint64_t* W3 = (uint64_t*)(ws + OFF_W3);
    uint64_t* W4 = (uint64_t*)(ws + OFF_W4);
    uint32_t* A1 = (uint32_t*)(ws + OFF_A1);
    uint64_t* A2 = (uint64_t*)(ws + OFF_A2);
    uint64_t* A3 = (uint64_t*)(ws + OFF_A3);
    uint64_t* A4 = (uint64_t*)(ws + OFF_A4);

    // 6344 waves: 6336 pack words + 8 BN waves -> 1586 blocks of 256
    hipLaunchKernelGGL(k_prep, dim3(1586), dim3(256), 0, stream,
                       w2, w3, w4,
                       g1, b1, m1, v1, g2, b2, m2, v2,
                       g3, b3, m3, v3, g4, b4, m4, v4,
                       S1, S2, S3, S4, W2, W3, W4);
    hipLaunchKernelGGL(k_conv1, dim3(3136), dim3(256), 0, stream, x, w1, S1, A1);
    hipLaunchKernelGGL(k_conv2, dim3(1568), dim3(256), 0, stream, A1, W2, S2, A2);
    hipLaunchKernelGGL(k_conv3, dim3(784),  dim3(256), 0, stream, A2, W3, S3, A3);
    hipLaunchKernelGGL(k_conv4, dim3(392),  dim3(256), 0, stream, A3, W4, S4, A4);
    hipLaunchKernelGGL(k_tail,  dim3(32),   dim3(256), 0, stream, A4, fcw, fcb, out);
}